// Round 5
// baseline (100.012 us; speedup 1.0000x reference)
//
#include <hip/hip_runtime.h>

// N = 4096 bodies, 2D. Broad phase keeps first 4N row-major AABB hits,
// exact phase keeps first N true penetrations, resolve is last-write-wins.
#define NB 4096
#define KBROAD (4 * NB)   // 16384
#define KEXACT NB         // 4096
typedef unsigned long long u64;

// ---------------------------------------------------------------------------
// K1: broad-phase counts + per-row hit bitmasks. 2 rows per wave.
// Grid: 512 blocks x 256 threads = 2048 waves.
// ---------------------------------------------------------------------------
__global__ __launch_bounds__(256) void count_kernel(
    const float2* __restrict__ pos, const float* __restrict__ rad,
    int* __restrict__ row_counts, u64* __restrict__ masks) {
  int gid = blockIdx.x * blockDim.x + threadIdx.x;
  int wave = gid >> 6;
  int lane = gid & 63;
  int r0 = wave * 2;          // rows r0, r0+1
  float2 p0 = pos[r0], p1 = pos[r0 + 1];
  float ra0 = rad[r0], ra1 = rad[r0 + 1];
  u64 mw0 = 0, mw1 = 0;       // lane c keeps the mask word of chunk c
  int c0 = 0, c1 = 0;
  for (int c = 0; c < 64; ++c) {
    int j = c * 64 + lane;
    float2 pj = pos[j];
    float rj = rad[j];
    float rs0 = ra0 + rj, rs1 = ra1 + rj;
    bool h0 = (j != r0) && (fabsf(p0.x - pj.x) <= rs0) && (fabsf(p0.y - pj.y) <= rs0);
    bool h1 = (j != r0 + 1) && (fabsf(p1.x - pj.x) <= rs1) && (fabsf(p1.y - pj.y) <= rs1);
    u64 m0 = __ballot(h0);
    u64 m1 = __ballot(h1);
    if (lane == c) { mw0 = m0; mw1 = m1; }
    c0 += __popcll(m0);
    c1 += __popcll(m1);
  }
  masks[(size_t)r0 * 64 + lane] = mw0;          // coalesced 512 B per row
  masks[(size_t)(r0 + 1) * 64 + lane] = mw1;
  if (lane == 0) { row_counts[r0] = c0; row_counts[r0 + 1] = c1; }
}

// ---------------------------------------------------------------------------
// K2: redundant per-block exclusive scan of row counts, then fill this
// block's 16 rows from stored masks (per-lane bit-walk) with the exact
// circle test inline. For every placed broad rank writes hit[rank] (0/1);
// for penetrating pairs also penvec[rank] and packed (i,j).
// Grid: 256 blocks x 256 threads. rb is TRANSPOSED to avoid bank conflicts.
// ---------------------------------------------------------------------------
__global__ __launch_bounds__(256) void fill_kernel(
    const float2* __restrict__ pos, const float* __restrict__ rad,
    const int* __restrict__ row_counts, const u64* __restrict__ masks,
    float2* __restrict__ penvec, unsigned* __restrict__ pij,
    int* __restrict__ hit) {
  __shared__ int rb[NB];     // transposed row-base table (16 KB)
  __shared__ int wsum[4];
  int t = threadIdx.x;
  int wv = t >> 6, lane = t & 63;
  // ---- stage 1: exclusive scan of 4096 counts (redundant per block).
  int c[16], s = 0;
  #pragma unroll
  for (int k = 0; k < 16; ++k) { c[k] = row_counts[t * 16 + k]; s += c[k]; }
  int v = s;  // wave inclusive scan
  #pragma unroll
  for (int off = 1; off < 64; off <<= 1) {
    int u = __shfl_up(v, off);
    if (lane >= off) v += u;
  }
  if (lane == 63) wsum[wv] = v;
  __syncthreads();
  int wbase = 0;
  #pragma unroll
  for (int w = 0; w < 4; ++w) if (w < wv) wbase += wsum[w];
  int run = wbase + v - s;   // exclusive base of thread t's first row
  #pragma unroll
  for (int k = 0; k < 16; ++k) { rb[k * 256 + t] = run; run += c[k]; }
  __syncthreads();
  // ---- stage 2: fill 4 rows per wave, lane c owns chunk c of the row.
  for (int q = 0; q < 4; ++q) {
    int r = blockIdx.x * 16 + wv * 4 + q;
    int rowbase = rb[(r & 15) * 256 + (r >> 4)];   // uniform across wave
    if (rowbase >= KBROAD) continue;               // uniform branch
    u64 myw = masks[(size_t)r * 64 + lane];
    int cnt = __popcll(myw);
    int v2 = cnt;
    #pragma unroll
    for (int off = 1; off < 64; off <<= 1) {
      int u = __shfl_up(v2, off);
      if (lane >= off) v2 += u;
    }
    int rank = rowbase + v2 - cnt;                 // base rank of my chunk
    if (!myw) continue;                            // per-lane; no wave ops below
    float2 pr = pos[r];
    float rr = rad[r];
    u64 m = myw;
    while (m && rank < KBROAD) {
      int b = __builtin_ctzll(m);
      m &= m - 1;
      int j = (lane << 6) + b;
      // exact circle test, rn ops to bit-match numpy (no FMA contraction)
      float2 pj = pos[j];
      float dx = pr.x - pj.x, dy = pr.y - pj.y;
      float ss = __fadd_rn(__fadd_rn(__fmul_rn(dx, dx), __fmul_rn(dy, dy)), 1e-12f);
      float dist = __fsqrt_rn(ss);
      float pen = __fsub_rn(__fadd_rn(rr, rad[j]), dist);
      int h = (pen > 0.0f) ? 1 : 0;
      hit[rank] = h;
      if (h) {
        float sc = __fdiv_rn(pen, dist);
        penvec[rank] = make_float2(__fmul_rn(dx, sc), __fmul_rn(dy, sc));
        pij[rank] = ((unsigned)r << 16) | (unsigned)j;
      }
      ++rank;
    }
  }
}

// ---------------------------------------------------------------------------
// K3: exact compaction + resolve in ONE 1024-thread block. All state (ev,
// last_i, last_j) in LDS; 16 slots/thread; 2-barrier block scan; no loop-
// carried global dependencies.
// ---------------------------------------------------------------------------
__global__ __launch_bounds__(1024) void final_kernel(
    const float2* __restrict__ pos, const int* __restrict__ row_counts,
    const int* __restrict__ hit, const unsigned* __restrict__ pij,
    const float2* __restrict__ penvec, float2* __restrict__ out) {
  __shared__ int last_i[NB];      // 16 KB
  __shared__ int last_j[NB];      // 16 KB
  __shared__ float2 ev[KEXACT];   // 32 KB
  __shared__ int wsum[16];
  __shared__ int wscan[16];
  int t = threadIdx.x;
  int wv = t >> 6, lane = t & 63;
  for (int b = t; b < NB; b += 1024) { last_i[b] = -1; last_j[b] = -1; }

  // total broad hits (block reduce of row_counts), clamped to KBROAD.
  int ps = row_counts[4 * t] + row_counts[4 * t + 1] +
           row_counts[4 * t + 2] + row_counts[4 * t + 3];
  #pragma unroll
  for (int off = 32; off; off >>= 1) ps += __shfl_down(ps, off);
  if (lane == 0) wsum[wv] = ps;
  __syncthreads();
  int total = 0;
  #pragma unroll
  for (int w = 0; w < 16; ++w) total += wsum[w];
  if (total > KBROAD) total = KBROAD;

  // per-thread: 16 slots, gather hit flags.
  int base = t * 16;
  int cnt = 0;
  unsigned hm = 0;
  #pragma unroll
  for (int k = 0; k < 16; ++k) {
    int s = base + k;
    int h = (s < total) ? hit[s] : 0;
    cnt += h;
    hm |= (unsigned)h << k;
  }
  // block scan of cnt (2 barriers).
  int v = cnt;
  #pragma unroll
  for (int off = 1; off < 64; off <<= 1) {
    int u = __shfl_up(v, off);
    if (lane >= off) v += u;
  }
  if (lane == 63) wscan[wv] = v;
  __syncthreads();
  int wbase = 0;
  #pragma unroll
  for (int w = 0; w < 16; ++w) if (w < wv) wbase += wscan[w];
  int rank = wbase + v - cnt;   // exclusive base of my first hit

  // place my hits.
  #pragma unroll
  for (int k = 0; k < 16; ++k) {
    if ((hm >> k) & 1u) {
      if (rank < KEXACT) {
        int s = base + k;
        ev[rank] = penvec[s];
        unsigned p = pij[s];
        atomicMax(&last_i[p >> 16], rank);
        atomicMax(&last_j[p & 0xFFFFu], rank);
      }
      ++rank;
    }
  }
  __syncthreads();

  // resolve: j-scatter wins over i-scatter; both read ORIGINAL pos.
  for (int b = t; b < NB; b += 1024) {
    float2 p = pos[b];
    int lj = last_j[b], li = last_i[b];
    float2 o = p;
    if (lj >= 0) {
      o.x = __fsub_rn(p.x, __fmul_rn(0.5f, ev[lj].x));
      o.y = __fsub_rn(p.y, __fmul_rn(0.5f, ev[lj].y));
    } else if (li >= 0) {
      o.x = __fadd_rn(p.x, __fmul_rn(0.5f, ev[li].x));
      o.y = __fadd_rn(p.y, __fmul_rn(0.5f, ev[li].y));
    }
    out[b] = o;
  }
}

// ---------------------------------------------------------------------------
extern "C" void kernel_launch(void* const* d_in, const int* in_sizes, int n_in,
                              void* d_out, int out_size, void* d_ws, size_t ws_size,
                              hipStream_t stream) {
  const float2* pos = (const float2*)d_in[0];
  const float* rad = (const float*)d_in[1];
  float2* out = (float2*)d_out;

  // Workspace layout (~2.3 MB of the ws).
  u64* masks = (u64*)d_ws;                              // NB*64 u64 = 2 MB
  float2* penvec = (float2*)(masks + (size_t)NB * 64);  // KBROAD float2
  int* row_counts = (int*)(penvec + KBROAD);            // NB
  unsigned* pij = (unsigned*)(row_counts + NB);         // KBROAD
  int* hit = (int*)(pij + KBROAD);                      // KBROAD

  count_kernel<<<512, 256, 0, stream>>>(pos, rad, row_counts, masks);
  fill_kernel<<<256, 256, 0, stream>>>(pos, rad, row_counts, masks, penvec,
                                       pij, hit);
  final_kernel<<<1, 1024, 0, stream>>>(pos, row_counts, hit, pij, penvec, out);
}